// Round 4
// baseline (764.983 us; speedup 1.0000x reference)
//
#include <hip/hip_runtime.h>
#include <hip/hip_cooperative_groups.h>
#include <math.h>

namespace cg = cooperative_groups;

#define H   1024
#define H2  2048
#define L   100
#define V   50257
#define NB  512
#define BS  256

// ws float offsets (16B aligned)
#define WS_ATT   0      // 100: attn logits
#define WS_CTX   128    // 1024: context
#define WS_X     1280   // 1024: relu(combine)
#define WS_GI    2304   // 6144: gru gate dots, gi[gate*1024 + j]
#define WS_HNEW  8448   // 1024: h_new
#define WS_PART  9472   // 2*NB: per-block (max, sumexp)

typedef float floatx4 __attribute__((ext_vector_type(4)));

__device__ __forceinline__ float wave_reduce_sum(float v) {
#pragma unroll
    for (int off = 32; off > 0; off >>= 1) v += __shfl_down(v, off);
    return v;
}

__device__ __forceinline__ float dot4(const float4 a, const float4 b) {
    return a.x * b.x + a.y * b.y + a.z * b.z + a.w * b.w;
}

__global__ __launch_bounds__(BS, 2)
void k_fused(const int* __restrict__ tok,
             const float* __restrict__ hidden,
             const float* __restrict__ enc,
             const float* __restrict__ emb,
             const float* __restrict__ attn_W,
             const float* __restrict__ attn_b,
             const float* __restrict__ comb_W,
             const float* __restrict__ comb_b,
             const float* __restrict__ W_ih,
             const float* __restrict__ W_hh,
             const float* __restrict__ b_ih,
             const float* __restrict__ b_hh,
             const float* __restrict__ out_W,
             const float* __restrict__ out_b,
             float* __restrict__ out,
             float* __restrict__ ws) {
    cg::grid_group grid = cg::this_grid();
    const int b = blockIdx.x;
    const int t = threadIdx.x;          // 256
    const int wave = t >> 6, lane = t & 63;
    const float* __restrict__ e = emb + (size_t)tok[0] * H;

    __shared__ float shv[H];            // h_new stage for big gemv
    __shared__ float sl[128];           // softmax scratch
    __shared__ float shw[L];            // softmax weights
    __shared__ float red[8];            // block reduce scratch

    // ---------- P1: attn logits (blocks 0..99, one logit each) ----------
    if (b < L) {
        const float* __restrict__ row = attn_W + (size_t)b * H2;
        const int i = t * 4;            // [0,1024)
        float4 w0 = *(const float4*)(row + i);
        float4 v0 = *(const float4*)(e + i);
        float4 w1 = *(const float4*)(row + H + i);
        float4 v1 = *(const float4*)(hidden + i);
        float acc = dot4(w0, v0) + dot4(w1, v1);
        acc = wave_reduce_sum(acc);
        if (lane == 0) red[wave] = acc;
        __syncthreads();
        if (t == 0) ws[WS_ATT + b] = red[0] + red[1] + red[2] + red[3] + attn_b[b];
    }
    grid.sync();

    // ---------- P2: softmax(100) + context (blocks 0..7, 128 cols each) ----------
    if (b < 8) {
        float v = 0.f, ex = 0.f;
        if (t < 128) { v = (t < L) ? ws[WS_ATT + t] : -INFINITY; sl[t] = v; }
        __syncthreads();
        for (int s = 64; s > 0; s >>= 1) {
            if (t < s) sl[t] = fmaxf(sl[t], sl[t + s]);
            __syncthreads();
        }
        float m = sl[0];
        __syncthreads();
        if (t < 128) { ex = (t < L) ? expf(v - m) : 0.f; sl[t] = ex; }
        __syncthreads();
        for (int s = 64; s > 0; s >>= 1) {
            if (t < s) sl[t] += sl[t + s];
            __syncthreads();
        }
        float denom = sl[0];
        if (t < L) {
            float w = ex / denom;
            shw[t] = w;
            if (b == 0) out[V + H + t] = w;    // attn_weights output
        }
        __syncthreads();
        if (t < 128) {
            const int h = b * 128 + t;
            float acc = 0.f;
#pragma unroll 4
            for (int l = 0; l < L; ++l) acc += shw[l] * enc[(size_t)l * H + h];
            ws[WS_CTX + h] = acc;
        }
    }
    grid.sync();

    // ---------- P3: combine (blocks 0..255, wave per row) ----------
    if (b < 256) {
        const int j = b * 4 + wave;
        const float* __restrict__ ctx = ws + WS_CTX;
        const float* __restrict__ row = comb_W + (size_t)j * H2;
        float acc = 0.f;
#pragma unroll
        for (int it = 0; it < 8; ++it) {
            const int i = it * 256 + lane * 4;
            float4 w = *(const float4*)(row + i);
            const float* __restrict__ src = (i < H) ? (e + i) : (ctx + (i - H));
            float4 v = *(const float4*)src;
            acc += dot4(w, v);
        }
        acc = wave_reduce_sum(acc);
        if (lane == 0) ws[WS_X + j] = fmaxf(acc + comb_b[j], 0.f);
    }
    grid.sync();

    // ---------- P4a: GRU gate dots (6144 wave-dots over 2048 waves x 3) ----------
    {
        const int g = b * 4 + wave;
#pragma unroll
        for (int it = 0; it < 3; ++it) {
            const int task = it * 2048 + g;       // = gate*1024 + j
            const int gate = task >> 10;
            const int j = task & 1023;
            const float* __restrict__ vec = (gate < 3) ? (ws + WS_X) : hidden;
            const float* __restrict__ row = (gate < 3)
                ? (W_ih + ((size_t)gate * H + j) * H)
                : (W_hh + ((size_t)(gate - 3) * H + j) * H);
            float acc = 0.f;
#pragma unroll
            for (int k = 0; k < 4; ++k) {
                const int i = k * 256 + lane * 4;
                float4 a = *(const float4*)(row + i);
                float4 v = *(const float4*)(vec + i);
                acc += dot4(a, v);
            }
            acc = wave_reduce_sum(acc);
            if (lane == 0) ws[WS_GI + task] = acc;
        }
    }
    grid.sync();

    // ---------- P4b: GRU gate math (blocks 0..3, thread per j) ----------
    if (b < 4) {
        const int j = b * 256 + t;
        const float* __restrict__ gi = ws + WS_GI;
        float ir  = gi[j]            + b_ih[j];
        float iz  = gi[H + j]        + b_ih[H + j];
        float inn = gi[2 * H + j]    + b_ih[2 * H + j];
        float hr  = gi[3 * H + j]    + b_hh[j];
        float hz  = gi[4 * H + j]    + b_hh[H + j];
        float hn  = gi[5 * H + j]    + b_hh[2 * H + j];
        float r = 1.f / (1.f + expf(-(ir + hr)));
        float z = 1.f / (1.f + expf(-(iz + hz)));
        float n = tanhf(inn + r * hn);
        float hnew = (1.f - z) * n + z * hidden[j];
        out[V + j]      = hnew;
        ws[WS_HNEW + j] = hnew;
    }
    grid.sync();

    // ---------- P5: big GEMV + fused per-block (m,s) partial ----------
    {
        *(float4*)(shv + t * 4) = *(const float4*)(ws + WS_HNEW + t * 4);
        __syncthreads();
        const int g = b * 4 + wave;
        float m = -INFINITY, s = 0.f;       // lane 0 only
#pragma unroll 1
        for (int pass = 0; pass < 7; ++pass) {
            const int r0 = (pass * 2048 + g) * 4;
            if (r0 >= V) break;
            const float* __restrict__ base = out_W + (size_t)r0 * H;
            float acc0 = 0.f, acc1 = 0.f, acc2 = 0.f, acc3 = 0.f;
            if (r0 + 3 < V) {
#pragma unroll
                for (int it = 0; it < 4; ++it) {
                    const int i = it * 256 + lane * 4;
                    float4 bv = *(const float4*)(shv + i);
                    floatx4 a0 = __builtin_nontemporal_load((const floatx4*)(base + i));
                    floatx4 a1 = __builtin_nontemporal_load((const floatx4*)(base + H + i));
                    floatx4 a2 = __builtin_nontemporal_load((const floatx4*)(base + 2 * H + i));
                    floatx4 a3 = __builtin_nontemporal_load((const floatx4*)(base + 3 * H + i));
                    acc0 += a0.x * bv.x + a0.y * bv.y + a0.z * bv.z + a0.w * bv.w;
                    acc1 += a1.x * bv.x + a1.y * bv.y + a1.z * bv.z + a1.w * bv.w;
                    acc2 += a2.x * bv.x + a2.y * bv.y + a2.z * bv.z + a2.w * bv.w;
                    acc3 += a3.x * bv.x + a3.y * bv.y + a3.z * bv.z + a3.w * bv.w;
                }
            } else {
                for (int it = 0; it < 4; ++it) {
                    const int i = it * 256 + lane * 4;
                    float4 bv = *(const float4*)(shv + i);
                    if (r0 + 0 < V) { float4 a = *(const float4*)(base + i);           acc0 += dot4(a, bv); }
                    if (r0 + 1 < V) { float4 a = *(const float4*)(base + H + i);       acc1 += dot4(a, bv); }
                    if (r0 + 2 < V) { float4 a = *(const float4*)(base + 2 * H + i);   acc2 += dot4(a, bv); }
                    if (r0 + 3 < V) { float4 a = *(const float4*)(base + 3 * H + i);   acc3 += dot4(a, bv); }
                }
            }
            acc0 = wave_reduce_sum(acc0);
            acc1 = wave_reduce_sum(acc1);
            acc2 = wave_reduce_sum(acc2);
            acc3 = wave_reduce_sum(acc3);
            if (lane == 0) {
                float lg[4] = {acc0, acc1, acc2, acc3};
#pragma unroll
                for (int r = 0; r < 4; ++r) {
                    const int row = r0 + r;
                    if (row < V) {
                        float l = lg[r] + out_b[row];
                        out[row] = l;
                        if (l > m) { s = s * expf(m - l) + 1.f; m = l; }
                        else       { s += expf(l - m); }
                    }
                }
            }
        }
        __syncthreads();   // reuse red[]
        if (lane == 0) { red[wave] = m; red[4 + wave] = s; }
        __syncthreads();
        if (t == 0) {
            float M = red[0], S = red[4];
#pragma unroll
            for (int i = 1; i < 4; ++i) {
                float M2 = fmaxf(M, red[i]);
                S = S * expf(M - M2) + red[4 + i] * expf(red[i] - M2);
                M = M2;
            }
            ws[WS_PART + 2 * b]     = M;
            ws[WS_PART + 2 * b + 1] = S;
        }
    }
    grid.sync();

    // ---------- P6: redundant LSE reduce per block + subtract ----------
    {
        const float* __restrict__ part = ws + WS_PART;
        // each thread merges pairs t and t+256 (all finite)
        float m1 = part[2 * t],         s1 = part[2 * t + 1];
        float m2 = part[2 * (t + 256)], s2 = part[2 * (t + 256) + 1];
        float m = fmaxf(m1, m2);
        float s = s1 * expf(m1 - m) + s2 * expf(m2 - m);
#pragma unroll
        for (int off = 32; off > 0; off >>= 1) {
            float mo = __shfl_down(m, off);
            float so = __shfl_down(s, off);
            float M = fmaxf(m, mo);
            s = s * expf(m - M) + so * expf(mo - M);
            m = M;
        }
        __syncthreads();
        if (lane == 0) { red[wave] = m; red[4 + wave] = s; }
        __syncthreads();
        if (t == 0) {
            float M = red[0], S = red[4];
#pragma unroll
            for (int i = 1; i < 4; ++i) {
                float M2 = fmaxf(M, red[i]);
                S = S * expf(M - M2) + red[4 + i] * expf(red[i] - M2);
                M = M2;
            }
            sl[0] = M + logf(S);
        }
        __syncthreads();
        const float c = sl[0];
        const int idx = b * BS + t;
        if (idx < V) out[idx] -= c;
    }
}

extern "C" void kernel_launch(void* const* d_in, const int* in_sizes, int n_in,
                              void* d_out, int out_size, void* d_ws, size_t ws_size,
                              hipStream_t stream) {
    const int*   tok    = (const int*)d_in[0];
    const float* hidden = (const float*)d_in[1];
    const float* enc    = (const float*)d_in[2];
    const float* emb    = (const float*)d_in[3];
    const float* attn_W = (const float*)d_in[4];
    const float* attn_b = (const float*)d_in[5];
    const float* comb_W = (const float*)d_in[6];
    const float* comb_b = (const float*)d_in[7];
    const float* W_ih   = (const float*)d_in[8];
    const float* W_hh   = (const float*)d_in[9];
    const float* b_ih   = (const float*)d_in[10];
    const float* b_hh   = (const float*)d_in[11];
    const float* out_W  = (const float*)d_in[12];
    const float* out_b  = (const float*)d_in[13];
    float* out = (float*)d_out;
    float* ws  = (float*)d_ws;

    void* args[] = {
        (void*)&tok, (void*)&hidden, (void*)&enc, (void*)&emb,
        (void*)&attn_W, (void*)&attn_b, (void*)&comb_W, (void*)&comb_b,
        (void*)&W_ih, (void*)&W_hh, (void*)&b_ih, (void*)&b_hh,
        (void*)&out_W, (void*)&out_b, (void*)&out, (void*)&ws
    };
    hipLaunchCooperativeKernel((const void*)k_fused, dim3(NB), dim3(BS),
                               args, 0, stream);
}